// Round 1
// baseline (198.328 us; speedup 1.0000x reference)
//
#include <hip/hip_runtime.h>
#include <math.h>

// E8S codebook quantization:
//   scores = 2 * X @ grid.T - grid_norm   [8192, 55650]
//   idx    = argmax(scores, axis=-1)      (first-max tiebreak, like np.argmax)
//   vals   = grid[idx]                    [8192, 8]  (fp32)
//   out2   = float(idx - 32768)           [8192]     (int16 value range, stored as f32)
//
// d_out layout (read back as one float32 buffer): [8192*8 vals][8192 idx floats]

constexpr int NROWS  = 8192;
constexpr int NCW    = 55650;
constexpr int NCHUNK = 32;
constexpr int CWPC   = (NCW + NCHUNK - 1) / NCHUNK;  // 1740 codewords / chunk

// Phase 1: each block = 512 rows x 1 codeword chunk. 2 rows per thread.
// Codeword index c is wave-uniform -> G/GN loads scalarize (s_load), leaving
// the VALU for the 8-FMA dot + argmax update per (row, codeword).
__global__ __launch_bounds__(256) void e8_partial(
    const float* __restrict__ X, const float* __restrict__ G,
    const float* __restrict__ GN,
    float* __restrict__ bscore, int* __restrict__ bidx) {
  const int tid = threadIdx.x;
  const int rb  = blockIdx.x;   // 16 row blocks of 512 rows
  const int ch  = blockIdx.y;   // codeword chunk
  const int r0  = rb * 512 + tid;
  const int r1  = r0 + 256;

  // load the two X rows into registers (2x float4 each)
  float x0[8], x1[8];
  {
    const float4* p0 = reinterpret_cast<const float4*>(X + (size_t)r0 * 8);
    const float4* p1 = reinterpret_cast<const float4*>(X + (size_t)r1 * 8);
    float4 a = p0[0], b = p0[1], c = p1[0], d = p1[1];
    x0[0]=a.x; x0[1]=a.y; x0[2]=a.z; x0[3]=a.w;
    x0[4]=b.x; x0[5]=b.y; x0[6]=b.z; x0[7]=b.w;
    x1[0]=c.x; x1[1]=c.y; x1[2]=c.z; x1[3]=c.w;
    x1[4]=d.x; x1[5]=d.y; x1[6]=d.z; x1[7]=d.w;
  }

  const int cbeg = ch * CWPC;
  const int cend = (cbeg + CWPC < NCW) ? (cbeg + CWPC) : NCW;

  float b0 = -INFINITY, b1 = -INFINITY;
  int   i0 = cbeg,      i1 = cbeg;

#pragma unroll 4
  for (int c = cbeg; c < cend; ++c) {
    const float* g = G + (size_t)c * 8;   // uniform address -> scalar loads
    const float gn = GN[c];
    const float g0 = g[0], g1 = g[1], g2 = g[2], g3 = g[3];
    const float g4 = g[4], g5 = g[5], g6 = g[6], g7 = g[7];

    float a0 = x0[0] * g0;
    a0 = fmaf(x0[1], g1, a0); a0 = fmaf(x0[2], g2, a0);
    a0 = fmaf(x0[3], g3, a0); a0 = fmaf(x0[4], g4, a0);
    a0 = fmaf(x0[5], g5, a0); a0 = fmaf(x0[6], g6, a0);
    a0 = fmaf(x0[7], g7, a0);
    float a1 = x1[0] * g0;
    a1 = fmaf(x1[1], g1, a1); a1 = fmaf(x1[2], g2, a1);
    a1 = fmaf(x1[3], g3, a1); a1 = fmaf(x1[4], g4, a1);
    a1 = fmaf(x1[5], g5, a1); a1 = fmaf(x1[6], g6, a1);
    a1 = fmaf(x1[7], g7, a1);

    const float s0 = fmaf(a0, 2.0f, -gn);
    const float s1 = fmaf(a1, 2.0f, -gn);
    if (s0 > b0) { b0 = s0; i0 = c; }   // strict > keeps FIRST max (np.argmax)
    if (s1 > b1) { b1 = s1; i1 = c; }
  }

  bscore[(size_t)r0 * NCHUNK + ch] = b0;
  bidx  [(size_t)r0 * NCHUNK + ch] = i0;
  bscore[(size_t)r1 * NCHUNK + ch] = b1;
  bidx  [(size_t)r1 * NCHUNK + ch] = i1;
}

// Phase 2: reduce the NCHUNK partials per row (ascending chunk order + strict >
// composes to a global first-max), gather codeword, write outputs.
__global__ __launch_bounds__(256) void e8_reduce(
    const float* __restrict__ G,
    const float* __restrict__ bscore, const int* __restrict__ bidx,
    float* __restrict__ out) {
  const int r = blockIdx.x * 256 + threadIdx.x;
  float best = -INFINITY;
  int   bi   = 0;
#pragma unroll
  for (int ch = 0; ch < NCHUNK; ++ch) {
    const float s = bscore[(size_t)r * NCHUNK + ch];
    const int   ix = bidx[(size_t)r * NCHUNK + ch];
    if (s > best) { best = s; bi = ix; }
  }
  const float4* g = reinterpret_cast<const float4*>(G + (size_t)bi * 8);
  float4 v0 = g[0], v1 = g[1];
  float4* o = reinterpret_cast<float4*>(out + (size_t)r * 8);
  o[0] = v0; o[1] = v1;
  out[(size_t)NROWS * 8 + r] = (float)(bi - 32768);
}

extern "C" void kernel_launch(void* const* d_in, const int* in_sizes, int n_in,
                              void* d_out, int out_size, void* d_ws, size_t ws_size,
                              hipStream_t stream) {
  const float* X  = (const float*)d_in[0];
  const float* G  = (const float*)d_in[1];
  const float* GN = (const float*)d_in[2];
  float* out = (float*)d_out;

  float* bscore = (float*)d_ws;                                   // 8192*32 f32 = 1 MB
  int*   bidx   = (int*)((char*)d_ws + (size_t)NROWS * NCHUNK * 4); // 1 MB

  e8_partial<<<dim3(NROWS / 512, NCHUNK), 256, 0, stream>>>(X, G, GN, bscore, bidx);
  e8_reduce<<<NROWS / 256, 256, 0, stream>>>(G, bscore, bidx, out);
}

// Round 2
// 124.445 us; speedup vs baseline: 1.5937x; 1.5937x over previous
//
#include <hip/hip_runtime.h>
#include <math.h>

// E8S codebook quantization:
//   scores = 2 * X @ grid.T - grid_norm   [8192, 55650]
//   idx    = argmax(scores, axis=-1)      (first-max tiebreak, like np.argmax)
//   vals   = grid[idx]                    [8192, 8]  (fp32)
//   out2   = float(idx - 32768)           [8192]
//
// d_out layout (read back as one float32 buffer): [8192*8 vals][8192 idx floats]
//
// Strategy: score = sum_j (2*x_j)*g_j starting from -gn  (11 VALU ops/row/cw).
// Per-(row,chunk) result folded into a global per-row packed uint64 via
// atomicMax: [ordered-float(score) << 32 | ~idx]. Equal scores -> larger ~idx
// wins -> smaller idx wins == np.argmax first-max semantics.

constexpr int NROWS  = 8192;
constexpr int NCW    = 55650;
constexpr int NCHUNK = 128;
constexpr int CWPC   = (NCW + NCHUNK - 1) / NCHUNK;  // 435 codewords / chunk

__device__ inline unsigned long long pack_key(float s, int idx) {
  unsigned int b = __float_as_uint(s);
  b = (b & 0x80000000u) ? ~b : (b | 0x80000000u);   // monotonic total order
  return ((unsigned long long)b << 32) | (unsigned int)(~idx);
}

__global__ __launch_bounds__(256) void e8_init(unsigned long long* best) {
  best[blockIdx.x * 256 + threadIdx.x] = 0ull;  // below any real encoded score
}

// Each block: 512 rows (2 per thread) x 1 chunk of 435 codewords.
// Grid: 16 x 128 = 2048 blocks -> 8192 waves -> full occupancy.
__global__ __launch_bounds__(256) void e8_partial(
    const float* __restrict__ X, const float* __restrict__ G,
    const float* __restrict__ GN, unsigned long long* __restrict__ best) {
  const int tid = threadIdx.x;
  const int rb  = blockIdx.x;   // 16 row blocks of 512 rows
  const int ch  = blockIdx.y;   // codeword chunk
  const int r0  = rb * 512 + tid;
  const int r1  = r0 + 256;

  // load two X rows, pre-scaled by 2 (folds the 2* into the dot product)
  float x0[8], x1[8];
  {
    const float4* p0 = reinterpret_cast<const float4*>(X + (size_t)r0 * 8);
    const float4* p1 = reinterpret_cast<const float4*>(X + (size_t)r1 * 8);
    float4 a = p0[0], b = p0[1], c = p1[0], d = p1[1];
    x0[0]=2.f*a.x; x0[1]=2.f*a.y; x0[2]=2.f*a.z; x0[3]=2.f*a.w;
    x0[4]=2.f*b.x; x0[5]=2.f*b.y; x0[6]=2.f*b.z; x0[7]=2.f*b.w;
    x1[0]=2.f*c.x; x1[1]=2.f*c.y; x1[2]=2.f*c.z; x1[3]=2.f*c.w;
    x1[4]=2.f*d.x; x1[5]=2.f*d.y; x1[6]=2.f*d.z; x1[7]=2.f*d.w;
  }

  const int cbeg = ch * CWPC;
  const int cend = (cbeg + CWPC < NCW) ? (cbeg + CWPC) : NCW;

  float b0 = -INFINITY, b1 = -INFINITY;
  int   i0 = cbeg,      i1 = cbeg;

#pragma unroll 4
  for (int c = cbeg; c < cend; ++c) {
    const float* g = G + (size_t)c * 8;   // wave-uniform -> s_load
    const float gn = GN[c];
    const float g0 = g[0], g1 = g[1], g2 = g[2], g3 = g[3];
    const float g4 = g[4], g5 = g[5], g6 = g[6], g7 = g[7];

    float s0 = fmaf(x0[0], g0, -gn);
    s0 = fmaf(x0[1], g1, s0); s0 = fmaf(x0[2], g2, s0);
    s0 = fmaf(x0[3], g3, s0); s0 = fmaf(x0[4], g4, s0);
    s0 = fmaf(x0[5], g5, s0); s0 = fmaf(x0[6], g6, s0);
    s0 = fmaf(x0[7], g7, s0);
    float s1 = fmaf(x1[0], g0, -gn);
    s1 = fmaf(x1[1], g1, s1); s1 = fmaf(x1[2], g2, s1);
    s1 = fmaf(x1[3], g3, s1); s1 = fmaf(x1[4], g4, s1);
    s1 = fmaf(x1[5], g5, s1); s1 = fmaf(x1[6], g6, s1);
    s1 = fmaf(x1[7], g7, s1);

    if (s0 > b0) { b0 = s0; i0 = c; }   // strict > keeps FIRST max within chunk
    if (s1 > b1) { b1 = s1; i1 = c; }
  }

  atomicMax(&best[r0], pack_key(b0, i0));
  atomicMax(&best[r1], pack_key(b1, i1));
}

__global__ __launch_bounds__(256) void e8_final(
    const float* __restrict__ G, const unsigned long long* __restrict__ best,
    float* __restrict__ out) {
  const int r = blockIdx.x * 256 + threadIdx.x;
  const unsigned long long k = best[r];
  const int idx = (int)(~(unsigned int)(k & 0xFFFFFFFFull));
  const float4* g = reinterpret_cast<const float4*>(G + (size_t)idx * 8);
  float4 v0 = g[0], v1 = g[1];
  float4* o = reinterpret_cast<float4*>(out + (size_t)r * 8);
  o[0] = v0; o[1] = v1;
  out[(size_t)NROWS * 8 + r] = (float)(idx - 32768);
}

extern "C" void kernel_launch(void* const* d_in, const int* in_sizes, int n_in,
                              void* d_out, int out_size, void* d_ws, size_t ws_size,
                              hipStream_t stream) {
  const float* X  = (const float*)d_in[0];
  const float* G  = (const float*)d_in[1];
  const float* GN = (const float*)d_in[2];
  float* out = (float*)d_out;
  unsigned long long* best = (unsigned long long*)d_ws;  // 8192 * 8B = 64 KB

  e8_init<<<NROWS / 256, 256, 0, stream>>>(best);
  e8_partial<<<dim3(NROWS / 512, NCHUNK), 256, 0, stream>>>(X, G, GN, best);
  e8_final<<<NROWS / 256, 256, 0, stream>>>(G, best, out);
}

// Round 3
// 105.421 us; speedup vs baseline: 1.8813x; 1.1805x over previous
//
#include <hip/hip_runtime.h>
#include <math.h>

// E8S codebook quantization via bf16 MFMA with exact 4-way split.
//   scores[r][c] = 2*X[r]·G[c] - ||G[c]||^2 ; idx = first-argmax over c.
// G coords are multiples of 0.25 (exact bf16). 2*X split into h+m+l+q bf16
// terms (exact, 24+ mantissa bits) stacked along K=32; G replicated 4x along
// K; C preloaded with -gn. One mfma_f32_16x16x32_bf16 = full biased score tile.
// Swapped operands: A=G-tile (M=codewords), B=X-splits (N=rows) so each lane's
// 4 D regs are 4 codewords of ONE row -> v_max3-friendly.
// Pass A: per-row max value (atomicMax, ordered-uint). Pass B: bit-identical
// recompute, score==rowmax -> atomicMin(index)  == np.argmax first-max.

typedef short short8 __attribute__((ext_vector_type(8)));
typedef float f32x4  __attribute__((ext_vector_type(4)));

constexpr int NROWS  = 8192;
constexpr int NCW    = 55650;
constexpr int NTILE  = 3479;          // ceil(NCW/16)
constexpr int NCWP   = NTILE * 16;    // 55664 (padded, pads score -inf)
constexpr int NCHUNK = 128;           // codeword-tile chunks (grid.y)
constexpr int RB     = 16;            // row blocks of 512 rows (grid.x)

// workspace layout (bytes)
constexpr size_t OFF_GB  = 0;                          // ushort Gb[NCWP*8]
constexpr size_t OFF_GNN = OFF_GB  + (size_t)NCWP*16;  // float  gnn[NCWP]
constexpr size_t OFF_XS  = OFF_GNN + (size_t)NCWP*4;   // ushort Xs[NROWS*4*8]
constexpr size_t OFF_RM  = OFF_XS  + (size_t)NROWS*64; // uint   rowmax[NROWS]
constexpr size_t OFF_BI  = OFF_RM  + (size_t)NROWS*4;  // int    bestidx[NROWS]
// total ~1.70 MB

__device__ inline unsigned short bf16_rne(float f) {
  unsigned int u = __float_as_uint(f);
  unsigned int r = u + 0x7FFFu + ((u >> 16) & 1u);
  return (unsigned short)(r >> 16);
}
__device__ inline float bf16_f(unsigned short h) {
  return __uint_as_float(((unsigned int)h) << 16);
}
__device__ inline unsigned int enc_ord(float f) {  // monotonic float->uint
  unsigned int u = __float_as_uint(f);
  return (u & 0x80000000u) ? ~u : (u | 0x80000000u);
}
__device__ inline float dec_ord(unsigned int e) {
  unsigned int u = (e & 0x80000000u) ? (e & 0x7FFFFFFFu) : ~e;
  return __uint_as_float(u);
}

__global__ __launch_bounds__(256) void e8_prep(
    const float* __restrict__ X, const float* __restrict__ G,
    const float* __restrict__ GN, unsigned short* __restrict__ Gb,
    float* __restrict__ gnn, unsigned short* __restrict__ Xs,
    unsigned int* __restrict__ rowmax, int* __restrict__ bestidx) {
  int i = blockIdx.x * 256 + threadIdx.x;
  if (i < NCWP) {
    if (i < NCW) {
      for (int j = 0; j < 8; ++j) Gb[(size_t)i*8+j] = bf16_rne(G[(size_t)i*8+j]);
      gnn[i] = -GN[i];
    } else {
      for (int j = 0; j < 8; ++j) Gb[(size_t)i*8+j] = 0;
      gnn[i] = -INFINITY;   // pad codewords can never win
    }
  } else if (i < NCWP + NROWS) {
    int r = i - NCWP;
    for (int j = 0; j < 8; ++j) {
      float s = 2.0f * X[(size_t)r*8+j];           // exact (exp bump)
      unsigned short h = bf16_rne(s);  float r1 = s  - bf16_f(h);  // exact
      unsigned short m = bf16_rne(r1); float r2 = r1 - bf16_f(m);  // exact
      unsigned short l = bf16_rne(r2); float r3 = r2 - bf16_f(l);  // exact
      unsigned short q = bf16_rne(r3);                             // exact (<=3 bits left)
      Xs[((size_t)r*4 + 0)*8 + j] = h;
      Xs[((size_t)r*4 + 1)*8 + j] = m;
      Xs[((size_t)r*4 + 2)*8 + j] = l;
      Xs[((size_t)r*4 + 3)*8 + j] = q;
    }
    rowmax[r]  = 0u;          // < enc_ord of any real score (even -inf)
    bestidx[r] = 0x7FFFFFFF;
  }
}

// Per block: 4 waves x 8 row-tiles = 512 rows, one chunk of ~27 codeword tiles.
// Lane roles: c = lane&15 (A-row=codeword-in-tile AND B-col=X-row-in-tile),
// kg = lane>>4 (K-group = which split for B; replica index for A).
__global__ __launch_bounds__(256) void e8_passA(
    const unsigned short* __restrict__ Gb, const float* __restrict__ gnn,
    const unsigned short* __restrict__ Xs, unsigned int* __restrict__ rowmax) {
  const int lane = threadIdx.x & 63;
  const int wave = threadIdx.x >> 6;
  const int c = lane & 15, kg = lane >> 4;
  const int rt0 = blockIdx.x * 32 + wave * 8;

  short8 xf[8];
#pragma unroll
  for (int t = 0; t < 8; ++t) {
    int row = (rt0 + t) * 16 + c;
    xf[t] = *reinterpret_cast<const short8*>(Xs + ((size_t)row*4 + kg)*8);
  }

  const int ct0 = (blockIdx.y * NTILE) / NCHUNK;
  const int ct1 = ((blockIdx.y + 1) * NTILE) / NCHUNK;

  float b[8];
#pragma unroll
  for (int t = 0; t < 8; ++t) b[t] = -INFINITY;

  for (int ct = ct0; ct < ct1; ++ct) {
    short8 af = *reinterpret_cast<const short8*>(Gb + (size_t)(ct*16 + c)*8);
    f32x4  cf = *reinterpret_cast<const f32x4*>(gnn + ct*16 + kg*4);
#pragma unroll
    for (int t = 0; t < 8; ++t) {
      f32x4 d = __builtin_amdgcn_mfma_f32_16x16x32_bf16(af, xf[t], cf, 0, 0, 0);
      b[t] = fmaxf(fmaxf(d[0], d[1]), fmaxf(fmaxf(d[2], d[3]), b[t]));
    }
  }

#pragma unroll
  for (int t = 0; t < 8; ++t) {
    float v = b[t];
    v = fmaxf(v, __shfl_xor(v, 16, 64));
    v = fmaxf(v, __shfl_xor(v, 32, 64));
    if (lane < 16) atomicMax(&rowmax[(size_t)(rt0 + t)*16 + c], enc_ord(v));
  }
}

__global__ __launch_bounds__(256) void e8_passB(
    const unsigned short* __restrict__ Gb, const float* __restrict__ gnn,
    const unsigned short* __restrict__ Xs, const unsigned int* __restrict__ rowmax,
    int* __restrict__ bestidx) {
  const int lane = threadIdx.x & 63;
  const int wave = threadIdx.x >> 6;
  const int c = lane & 15, kg = lane >> 4;
  const int rt0 = blockIdx.x * 32 + wave * 8;

  short8 xf[8];
  float  rmx[8];
#pragma unroll
  for (int t = 0; t < 8; ++t) {
    int row = (rt0 + t) * 16 + c;
    xf[t]  = *reinterpret_cast<const short8*>(Xs + ((size_t)row*4 + kg)*8);
    rmx[t] = dec_ord(rowmax[row]);
  }

  const int ct0 = (blockIdx.y * NTILE) / NCHUNK;
  const int ct1 = ((blockIdx.y + 1) * NTILE) / NCHUNK;

  for (int ct = ct0; ct < ct1; ++ct) {
    short8 af = *reinterpret_cast<const short8*>(Gb + (size_t)(ct*16 + c)*8);
    f32x4  cf = *reinterpret_cast<const f32x4*>(gnn + ct*16 + kg*4);
#pragma unroll
    for (int t = 0; t < 8; ++t) {
      f32x4 d = __builtin_amdgcn_mfma_f32_16x16x32_bf16(af, xf[t], cf, 0, 0, 0);
      const int base = ct * 16 + kg * 4;
      const size_t row = (size_t)(rt0 + t) * 16 + c;
      if (d[0] == rmx[t]) atomicMin(&bestidx[row], base + 0);
      if (d[1] == rmx[t]) atomicMin(&bestidx[row], base + 1);
      if (d[2] == rmx[t]) atomicMin(&bestidx[row], base + 2);
      if (d[3] == rmx[t]) atomicMin(&bestidx[row], base + 3);
    }
  }
}

__global__ __launch_bounds__(256) void e8_final(
    const float* __restrict__ G, const int* __restrict__ bestidx,
    float* __restrict__ out) {
  const int r = blockIdx.x * 256 + threadIdx.x;
  const int idx = bestidx[r];
  const float4* g = reinterpret_cast<const float4*>(G + (size_t)idx * 8);
  float4 v0 = g[0], v1 = g[1];
  float4* o = reinterpret_cast<float4*>(out + (size_t)r * 8);
  o[0] = v0; o[1] = v1;
  out[(size_t)NROWS * 8 + r] = (float)(idx - 32768);
}

extern "C" void kernel_launch(void* const* d_in, const int* in_sizes, int n_in,
                              void* d_out, int out_size, void* d_ws, size_t ws_size,
                              hipStream_t stream) {
  const float* X  = (const float*)d_in[0];
  const float* G  = (const float*)d_in[1];
  const float* GN = (const float*)d_in[2];
  float* out = (float*)d_out;

  char* ws = (char*)d_ws;
  unsigned short* Gb      = (unsigned short*)(ws + OFF_GB);
  float*          gnn     = (float*)(ws + OFF_GNN);
  unsigned short* Xs      = (unsigned short*)(ws + OFF_XS);
  unsigned int*   rowmax  = (unsigned int*)(ws + OFF_RM);
  int*            bestidx = (int*)(ws + OFF_BI);

  e8_prep<<<(NCWP + NROWS + 255) / 256, 256, 0, stream>>>(X, G, GN, Gb, gnn, Xs, rowmax, bestidx);
  e8_passA<<<dim3(RB, NCHUNK), 256, 0, stream>>>(Gb, gnn, Xs, rowmax);
  e8_passB<<<dim3(RB, NCHUNK), 256, 0, stream>>>(Gb, gnn, Xs, rowmax, bestidx);
  e8_final<<<NROWS / 256, 256, 0, stream>>>(G, bestidx, out);
}

// Round 4
// 69.475 us; speedup vs baseline: 2.8547x; 1.5174x over previous
//
#include <hip/hip_runtime.h>
#include <math.h>

// E8S codebook quantization via bf16 MFMA, exact 3-way split, single pass.
//   scores[r][c] = 2*X[r]·G[c] - ||G[c]||^2 ; idx = first-argmax over c.
// G coords are multiples of 0.25 (exact in bf16). 2*X = h+m+l exactly
// (each bf16 split removes >=8 of the 24 mantissa bits; residual after 3 is 0).
// K=32 = 8 dims x {h,m,l,0}; G replicated along K; C preloaded with -gn.
// One mfma_f32_16x16x32_bf16 => biased 16x16 score tile. Swapped operands
// (A=G, B=X) put 4 codewords of ONE row in each lane's 4 D regs.
// Per-MFMA argmax: m=max4(d) + rare branchy slot-resolve (first-match =>
// smallest idx). Global merge: packed u64 atomicMax (score-ordered, ~idx low)
// == np.argmax first-max semantics.

typedef short short8 __attribute__((ext_vector_type(8)));
typedef float f32x4  __attribute__((ext_vector_type(4)));

constexpr int NROWS  = 8192;
constexpr int NCW    = 55650;
constexpr int NTILE  = 3479;          // ceil(NCW/16)
constexpr int NCWP   = NTILE * 16;    // 55664 (pads score -inf)
constexpr int NCHUNK = 128;           // codeword-tile chunks (grid.y)
constexpr int RB     = 16;            // row blocks of 512 rows (grid.x)

// workspace layout (bytes)
constexpr size_t OFF_GB  = 0;                          // ushort Gb[NCWP*8]
constexpr size_t OFF_GNN = OFF_GB  + (size_t)NCWP*16;  // float  gnn[NCWP]
constexpr size_t OFF_XS  = OFF_GNN + (size_t)NCWP*4;   // ushort Xs[NROWS*4*8]
constexpr size_t OFF_B   = OFF_XS  + (size_t)NROWS*64; // u64    best[NROWS]

__device__ inline unsigned short bf16_rne(float f) {
  unsigned int u = __float_as_uint(f);
  unsigned int r = u + 0x7FFFu + ((u >> 16) & 1u);
  return (unsigned short)(r >> 16);
}
__device__ inline float bf16_f(unsigned short h) {
  return __uint_as_float(((unsigned int)h) << 16);
}
__device__ inline unsigned int enc_ord(float f) {  // monotonic float->uint
  unsigned int u = __float_as_uint(f);
  return (u & 0x80000000u) ? ~u : (u | 0x80000000u);
}

__global__ __launch_bounds__(256) void e8_prep(
    const float* __restrict__ X, const float* __restrict__ G,
    const float* __restrict__ GN, unsigned short* __restrict__ Gb,
    float* __restrict__ gnn, unsigned short* __restrict__ Xs,
    unsigned long long* __restrict__ best) {
  int i = blockIdx.x * 256 + threadIdx.x;
  if (i < NCWP) {
    if (i < NCW) {
      for (int j = 0; j < 8; ++j) Gb[(size_t)i*8+j] = bf16_rne(G[(size_t)i*8+j]);
      gnn[i] = -GN[i];
    } else {
      for (int j = 0; j < 8; ++j) Gb[(size_t)i*8+j] = 0;
      gnn[i] = -INFINITY;   // pad codewords can never win
    }
  } else if (i < NCWP + NROWS) {
    int r = i - NCWP;
    for (int j = 0; j < 8; ++j) {
      float s = 2.0f * X[(size_t)r*8+j];           // exact
      unsigned short h = bf16_rne(s);  float r1 = s  - bf16_f(h);  // exact
      unsigned short m = bf16_rne(r1); float r2 = r1 - bf16_f(m);  // exact
      unsigned short l = bf16_rne(r2);             // r2 - l == 0 (proof in hdr)
      Xs[((size_t)r*4 + 0)*8 + j] = h;
      Xs[((size_t)r*4 + 1)*8 + j] = m;
      Xs[((size_t)r*4 + 2)*8 + j] = l;
      Xs[((size_t)r*4 + 3)*8 + j] = 0;
    }
    best[r] = 0ull;   // below enc_ord of any real score
  }
}

// Per block: 4 waves x 8 row-tiles = 512 rows, one chunk of ~27 codeword tiles.
// Lane roles: c = lane&15 (codeword-in-tile AND X-row-in-tile), kg = lane>>4.
__global__ __launch_bounds__(256) void e8_main(
    const unsigned short* __restrict__ Gb, const float* __restrict__ gnn,
    const unsigned short* __restrict__ Xs,
    unsigned long long* __restrict__ best) {
  const int lane = threadIdx.x & 63;
  const int wave = threadIdx.x >> 6;
  const int c = lane & 15, kg = lane >> 4;
  const int rt0 = blockIdx.x * 32 + wave * 8;

  short8 xf[8];
#pragma unroll
  for (int t = 0; t < 8; ++t) {
    int row = (rt0 + t) * 16 + c;
    xf[t] = *reinterpret_cast<const short8*>(Xs + ((size_t)row*4 + kg)*8);
  }

  const int ct0 = (blockIdx.y * NTILE) / NCHUNK;
  const int ct1 = ((blockIdx.y + 1) * NTILE) / NCHUNK;

  float b[8]; int bi[8];
#pragma unroll
  for (int t = 0; t < 8; ++t) { b[t] = -INFINITY; bi[t] = 0; }

  short8 af = *reinterpret_cast<const short8*>(Gb + (size_t)(ct0*16 + c)*8);
  f32x4  cf = *reinterpret_cast<const f32x4*>(gnn + ct0*16 + kg*4);

  for (int ct = ct0; ct < ct1; ++ct) {
    const int ctn = (ct + 1 < ct1) ? ct + 1 : ct0;   // prefetch next (clamped)
    short8 afn = *reinterpret_cast<const short8*>(Gb + (size_t)(ctn*16 + c)*8);
    f32x4  cfn = *reinterpret_cast<const f32x4*>(gnn + ctn*16 + kg*4);
    const int base = ct * 16 + kg * 4;
#pragma unroll
    for (int t = 0; t < 8; ++t) {
      f32x4 d = __builtin_amdgcn_mfma_f32_16x16x32_bf16(af, xf[t], cf, 0, 0, 0);
      float m = fmaxf(fmaxf(d[0], d[1]), fmaxf(d[2], d[3]));
      if (m > b[t]) {   // rare (exec-masked, usually whole-wave skipped)
        b[t] = m;
        bi[t] = base + ((m == d[0]) ? 0 : (m == d[1]) ? 1 : (m == d[2]) ? 2 : 3);
      }
    }
    af = afn; cf = cfn;
  }

#pragma unroll
  for (int t = 0; t < 8; ++t) {
    unsigned long long key =
        ((unsigned long long)enc_ord(b[t]) << 32) | (unsigned int)(~bi[t]);
    unsigned long long o = __shfl_xor(key, 16, 64); key = (o > key) ? o : key;
    o = __shfl_xor(key, 32, 64);                    key = (o > key) ? o : key;
    if (lane < 16) atomicMax(&best[(size_t)(rt0 + t) * 16 + c], key);
  }
}

__global__ __launch_bounds__(256) void e8_final(
    const float* __restrict__ G, const unsigned long long* __restrict__ best,
    float* __restrict__ out) {
  const int r = blockIdx.x * 256 + threadIdx.x;
  const int idx = (int)(~(unsigned int)(best[r] & 0xFFFFFFFFull));
  const float4* g = reinterpret_cast<const float4*>(G + (size_t)idx * 8);
  float4 v0 = g[0], v1 = g[1];
  float4* o = reinterpret_cast<float4*>(out + (size_t)r * 8);
  o[0] = v0; o[1] = v1;
  out[(size_t)NROWS * 8 + r] = (float)(idx - 32768);
}

extern "C" void kernel_launch(void* const* d_in, const int* in_sizes, int n_in,
                              void* d_out, int out_size, void* d_ws, size_t ws_size,
                              hipStream_t stream) {
  const float* X  = (const float*)d_in[0];
  const float* G  = (const float*)d_in[1];
  const float* GN = (const float*)d_in[2];
  float* out = (float*)d_out;

  char* ws = (char*)d_ws;
  unsigned short*     Gb   = (unsigned short*)(ws + OFF_GB);
  float*              gnn  = (float*)(ws + OFF_GNN);
  unsigned short*     Xs   = (unsigned short*)(ws + OFF_XS);
  unsigned long long* best = (unsigned long long*)(ws + OFF_B);

  e8_prep<<<(NCWP + NROWS + 255) / 256, 256, 0, stream>>>(X, G, GN, Gb, gnn, Xs, best);
  e8_main<<<dim3(RB, NCHUNK), 256, 0, stream>>>(Gb, gnn, Xs, best);
  e8_final<<<NROWS / 256, 256, 0, stream>>>(G, best, out);
}